// Round 4
// baseline (676.095 us; speedup 1.0000x reference)
//
#include <hip/hip_runtime.h>
#include <hip/hip_bf16.h>

// ---------------- problem constants ----------------
#define BATCH 32
#define NPATCH 196
#define PD 768      // patch dim
#define DH 3072     // hidden
#define FD 512      // feat dim
#define MH 128      // metanet hidden
#define NT 8        // num task vectors

typedef unsigned short u16;
typedef u16   u16x8  __attribute__((ext_vector_type(8)));
typedef short bf16x8 __attribute__((ext_vector_type(8)));
typedef float f32x4  __attribute__((ext_vector_type(4)));

__device__ __forceinline__ void async16(const void* g, void* l)
{
    __builtin_amdgcn_global_load_lds(
        (const __attribute__((address_space(1))) void*)g,
        (__attribute__((address_space(3))) void*)l, 16, 0, 0);
}

// =====================================================================
// bf16 MFMA batched GEMM:  C[z] = act(A[z] @ BT[z]^T + bias[z])
//   A [M,K] bf16, BT [N,K] bf16 (pre-transposed), C [M,N] bf16
// Tile 256x128, BK=32, 512 threads = 8 waves (4 row x 2 col), each wave
// 64x64 via 4x4 mfma_f32_16x16x32_bf16. Staging via global_load_lds x16B,
// unpadded LDS (wave-uniform dest requirement). N,K multiples of 128/32.
// =====================================================================
#define GBM 256
#define GBN 128
#define GBK 32

__global__ __launch_bounds__(512)
void gemm_bf16(const u16* __restrict__ A, const u16* __restrict__ BT,
               const float* __restrict__ bias, u16* __restrict__ C,
               int M, int N, int K,
               long sA, long sB, long sC, long sBias, int relu)
{
    const int z = blockIdx.z;
    A  += (long)z * sA;
    BT += (long)z * sB;
    C  += (long)z * sC;
    const float* bz = bias ? bias + (long)z * sBias : nullptr;

    __shared__ __align__(16) u16 As[GBM * GBK];   // 16 KB, contiguous rows (32 u16 = 64B)
    __shared__ __align__(16) u16 Bs[GBN * GBK];   // 8 KB

    const int tid  = threadIdx.x;
    const int lane = tid & 63;
    const int wave = tid >> 6;
    const int wr = (wave >> 1) * 64;   // 0,64,128,192
    const int wc = (wave & 1) * 64;    // 0,64

    const int m0 = blockIdx.y * GBM;
    const int n0 = blockIdx.x * GBN;

    f32x4 acc[4][4] = {};

    const int lrow = lane & 15;
    const int koff = (lane >> 4) * 8;

    for (int k0 = 0; k0 < K; k0 += GBK) {
        // ---- A: 256 rows x 4 chunks(16B) = 1024 chunks, 2 rounds of 512
#pragma unroll
        for (int r = 0; r < 2; ++r) {
            int chunk = r * 512 + tid;          // = r*512 + wave*64 + lane
            int row = chunk >> 2;
            int k8  = chunk & 3;
            int gm  = m0 + row; if (gm >= M) gm = M - 1;   // clamp (stores masked)
            async16(A + (long)gm * K + k0 + k8 * 8,
                    As + (size_t)(r * 512 + wave * 64) * 8);
        }
        // ---- B: 128 rows x 4 chunks = 512 chunks, 1 round
        {
            int row = tid >> 2;
            int k8  = tid & 3;
            async16(BT + (long)(n0 + row) * K + k0 + k8 * 8,
                    Bs + (size_t)(wave * 64) * 8);
        }
        __syncthreads();   // drains vmcnt (global_load_lds) before ds_read

        bf16x8 af[4], bfr[4];
#pragma unroll
        for (int i = 0; i < 4; ++i)
            af[i] = *(const bf16x8*)(&As[(wr + i * 16 + lrow) * GBK + koff]);
#pragma unroll
        for (int j = 0; j < 4; ++j)
            bfr[j] = *(const bf16x8*)(&Bs[(wc + j * 16 + lrow) * GBK + koff]);
#pragma unroll
        for (int i = 0; i < 4; ++i)
#pragma unroll
            for (int j = 0; j < 4; ++j)
                acc[i][j] = __builtin_amdgcn_mfma_f32_16x16x32_bf16(af[i], bfr[j], acc[i][j], 0, 0, 0);
        __syncthreads();
    }

    // epilogue: C/D layout col=lane&15, row=(lane>>4)*4+reg
    const int crow = (lane >> 4) * 4;
    const int ccol = lane & 15;
#pragma unroll
    for (int j = 0; j < 4; ++j) {
        int gn = n0 + wc + j * 16 + ccol;
        float bv = bz ? bz[gn] : 0.f;
#pragma unroll
        for (int i = 0; i < 4; ++i) {
#pragma unroll
            for (int rg = 0; rg < 4; ++rg) {
                int gm = m0 + wr + i * 16 + crow + rg;
                if (gm < M) {
                    float v = acc[i][j][rg] + bv;
                    if (relu) v = fmaxf(v, 0.f);
                    __hip_bfloat16 hv = __float2bfloat16(v);
                    C[(long)gm * N + gn] = *(u16*)&hv;
                }
            }
        }
    }
}

// =====================================================================
// skinny layer-3 split-K: outp[b,f] += sum_k Aeff[b,k] * Bz[k,f]
// z==0: Bz=W3, Aeff=A;  z>=1: Bz=dB[z-1], Aeff=cf[b,z-1]*A
// =====================================================================
#define L3CHUNK 128

__global__ __launch_bounds__(256)
void skinny3(const float* __restrict__ A, const float* __restrict__ B0,
             const float* __restrict__ dB, const float* __restrict__ cf,
             float* __restrict__ outp, int kchunk)
{
    const int z  = blockIdx.y;
    const int k0 = blockIdx.z * kchunk;
    const float* B = (z == 0) ? B0 : dB + (long)(z - 1) * DH * FD;

    __shared__ float Asl[BATCH][L3CHUNK];

    const int tid = threadIdx.x;
    const int n   = blockIdx.x * 64 + (tid & 63);
    const int bg  = tid >> 6;

    float acc[8] = {};

    for (int kc = 0; kc < kchunk; kc += L3CHUNK) {
#pragma unroll
        for (int r = 0; r < 16; ++r) {
            int idx = tid + r * 256;
            int b = idx >> 7;
            int k = idx & 127;
            float s = (z == 0) ? 1.f : cf[b * NT + z - 1];
            Asl[b][k] = s * A[(long)b * DH + k0 + kc + k];
        }
        __syncthreads();
#pragma unroll 4
        for (int k = 0; k < L3CHUNK; ++k) {
            float w = B[(long)(k0 + kc + k) * FD + n];
#pragma unroll
            for (int bb = 0; bb < 8; ++bb)
                acc[bb] = fmaf(Asl[bg * 8 + bb][k], w, acc[bb]);
        }
        __syncthreads();
    }
#pragma unroll
    for (int bb = 0; bb < 8; ++bb)
        atomicAdd(&outp[(long)(bg * 8 + bb) * FD + n], acc[bb]);
}

// ---------------- patchify -> bf16 ----------------
__global__ void patchify_bf(const float* __restrict__ x, u16* __restrict__ p, int total)
{
    int i = blockIdx.x * blockDim.x + threadIdx.x;
    if (i >= total) return;
    int d = i % PD;
    int rest = i / PD;
    int patch = rest % NPATCH;
    int b = rest / NPATCH;
    int c = d >> 8;
    int r = (d >> 4) & 15;
    int s = d & 15;
    int pr = patch / 14;
    int pc = patch % 14;
    float v = x[((long)(b * 3 + c) * 224 + (pr * 16 + r)) * 224 + (pc * 16 + s)];
    __hip_bfloat16 hv = __float2bfloat16(v);
    p[i] = *(u16*)&hv;
}

// ---------------- both shared-weight transposes in one launch ----------
// tiles: W1 has 24x24=576 (k-tiles x n-tiles), W2 has 24x96; blockIdx.x covers both
__global__ __launch_bounds__(256)
void wtrans2(const float* __restrict__ W1, u16* __restrict__ o1,
             const float* __restrict__ W2, u16* __restrict__ o2)
{
    const float* W; u16* outp; int K, N, t;
    if (blockIdx.x < 576) { W = W1; outp = o1; K = PD; N = PD;  t = blockIdx.x; }
    else                  { W = W2; outp = o2; K = PD; N = DH;  t = blockIdx.x - 576; }
    int nt = N / 32;
    int k0 = (t / nt) * 32;
    int n0 = (t % nt) * 32;

    __shared__ float Ws[32][33];
    const int tid = threadIdx.x;
#pragma unroll
    for (int r = 0; r < 4; ++r) {
        int idx = tid + r * 256;
        int kk = idx >> 5, nn = idx & 31;
        Ws[kk][nn] = W[(long)(k0 + kk) * N + n0 + nn];
    }
    __syncthreads();
#pragma unroll
    for (int r = 0; r < 4; ++r) {
        int idx = tid + r * 256;
        int kk = idx & 31, nn = idx >> 5;
        __hip_bfloat16 hv = __float2bfloat16(Ws[kk][nn]);
        outp[(long)(n0 + nn) * K + k0 + kk] = *(u16*)&hv;
    }
}

// ---------------- composed weights (bf16, transposed) ----------------
__global__ __launch_bounds__(256)
void compose_w(const float* __restrict__ W, const float* __restrict__ dW,
               const float* __restrict__ cf, u16* __restrict__ out,
               int K, int N)
{
    __shared__ float Ws[9][32][33];
    const int tid = threadIdx.x;
    const int k0 = blockIdx.x * 32;
    const int n0 = blockIdx.y * 32;
    const long tKN = (long)K * N;
#pragma unroll
    for (int r = 0; r < 4; ++r) {
        int idx = tid + r * 256;
        int kk = idx >> 5, nn = idx & 31;
        Ws[0][kk][nn] = W[(long)(k0 + kk) * N + n0 + nn];
    }
    for (int t = 0; t < NT; ++t) {
#pragma unroll
        for (int r = 0; r < 4; ++r) {
            int idx = tid + r * 256;
            int kk = idx >> 5, nn = idx & 31;
            Ws[t + 1][kk][nn] = dW[t * tKN + (long)(k0 + kk) * N + n0 + nn];
        }
    }
    __syncthreads();
    for (int b = 0; b < BATCH; ++b) {
        float cc[NT];
#pragma unroll
        for (int t = 0; t < NT; ++t) cc[t] = cf[b * NT + t];
#pragma unroll
        for (int r = 0; r < 4; ++r) {
            int idx = tid + r * 256;
            int kk = idx & 31, nn = idx >> 5;
            float v = Ws[0][kk][nn];
#pragma unroll
            for (int t = 0; t < NT; ++t) v = fmaf(cc[t], Ws[t + 1][kk][nn], v);
            __hip_bfloat16 hv = __float2bfloat16(v);
            out[((long)b * N + (n0 + nn)) * K + k0 + kk] = *(u16*)&hv;
        }
    }
}

// ---------------- composed biases b1b+b2b in one launch ----------------
__global__ void compose_bias2(const float* __restrict__ b1, const float* __restrict__ db1,
                              const float* __restrict__ b2, const float* __restrict__ db2,
                              const float* __restrict__ cf,
                              float* __restrict__ o1, float* __restrict__ o2)
{
    int i = blockIdx.x * blockDim.x + threadIdx.x;
    const int tot1 = BATCH * PD;
    const float* bs; const float* db; float* o; int N, j;
    if (i < tot1) { bs = b1; db = db1; o = o1; N = PD; j = i; }
    else {
        j = i - tot1;
        if (j >= BATCH * DH) return;
        bs = b2; db = db2; o = o2; N = DH;
    }
    int n = j % N, b = j / N;
    float v = bs[n];
#pragma unroll
    for (int t = 0; t < NT; ++t) v = fmaf(cf[b * NT + t], db[(long)t * N + n], v);
    o[j] = v;
}

// ---------------- bias init (single) ----------------
__global__ void compose_bias(const float* __restrict__ bsrc, const float* __restrict__ db,
                             const float* __restrict__ cf, float* __restrict__ out, int N)
{
    int i = blockIdx.x * blockDim.x + threadIdx.x;
    if (i >= BATCH * N) return;
    int n = i % N, b = i / N;
    float v = bsrc[n];
    if (db) {
#pragma unroll
        for (int t = 0; t < NT; ++t) v = fmaf(cf[b * NT + t], db[(long)t * N + n], v);
    }
    out[i] = v;
}

// ---------------- mean pool (vectorized u16x8) ----------------
__global__ void meanpool_bf(const u16* __restrict__ h2, float* __restrict__ out, int total8, int F)
{
    int i = blockIdx.x * blockDim.x + threadIdx.x;   // over BATCH*F/8
    if (i >= total8) return;
    int f8 = i % (F / 8);
    int b  = i / (F / 8);
    const u16* src = h2 + (long)b * NPATCH * F + f8 * 8;
    float s[8] = {};
    for (int p = 0; p < NPATCH; ++p) {
        u16x8 v = *(const u16x8*)(src + (long)p * F);
#pragma unroll
        for (int q = 0; q < 8; ++q) {
            u16 raw = v[q];
            __hip_bfloat16 hv = *(__hip_bfloat16*)&raw;
            s[q] += __bfloat162float(hv);
        }
    }
    float* o = out + (long)b * F + f8 * 8;
#pragma unroll
    for (int q = 0; q < 8; ++q) o[q] = s[q] * (1.0f / NPATCH);
}

// ---------------- metanet L1 ----------------
__global__ __launch_bounds__(256)
void hid_kernel(const float* __restrict__ base, const float* __restrict__ mW1,
                const float* __restrict__ mb1, float* __restrict__ hid)
{
    int gw   = blockIdx.x * 4 + (threadIdx.x >> 6);
    int lane = threadIdx.x & 63;
    int b = gw >> 7;
    int n = gw & 127;
    float s = 0.f;
#pragma unroll
    for (int i = 0; i < FD / 64; ++i) {
        int k = i * 64 + lane;
        s = fmaf(base[b * FD + k], mW1[k * MH + n], s);
    }
#pragma unroll
    for (int off = 32; off; off >>= 1) s += __shfl_down(s, off, 64);
    if (lane == 0) hid[gw] = fmaxf(s + mb1[n], 0.f);
}

// ---------------- metanet L2 ----------------
__global__ void coef_kernel(const float* __restrict__ hidden, const float* __restrict__ mW2,
                            const float* __restrict__ mb2, float* __restrict__ coefs)
{
    int i = threadIdx.x;
    int t = i & 7;
    int b = i >> 3;
    float s = mb2[t];
    for (int k = 0; k < MH; ++k)
        s = fmaf(hidden[b * MH + k], mW2[k * NT + t], s);
    coefs[i] = s;
}

// ---------------- launcher ----------------
extern "C" void kernel_launch(void* const* d_in, const int* in_sizes, int n_in,
                              void* d_out, int out_size, void* d_ws, size_t ws_size,
                              hipStream_t stream)
{
    const float* x   = (const float*)d_in[0];
    const float* W1  = (const float*)d_in[1];
    const float* b1  = (const float*)d_in[2];
    const float* W2  = (const float*)d_in[3];
    const float* b2  = (const float*)d_in[4];
    const float* W3  = (const float*)d_in[5];
    const float* b3  = (const float*)d_in[6];
    const float* dW1 = (const float*)d_in[7];
    const float* db1 = (const float*)d_in[8];
    const float* dW2 = (const float*)d_in[9];
    const float* db2 = (const float*)d_in[10];
    const float* dW3 = (const float*)d_in[11];
    const float* db3 = (const float*)d_in[12];
    const float* mW1 = (const float*)d_in[13];
    const float* mb1 = (const float*)d_in[14];
    const float* mW2 = (const float*)d_in[15];
    const float* mb2 = (const float*)d_in[16];
    float* out = (float*)d_out;
    (void)n_in; (void)in_sizes; (void)out_size; (void)ws_size;

    char* w = (char*)d_ws;
    auto carve = [&](size_t bytes) { void* q = (void*)w; w += (bytes + 255) & ~(size_t)255; return q; };
    const int M1 = BATCH * NPATCH;   // 6272

    u16*  p_bf  = (u16*)carve((size_t)M1 * PD * 2);
    u16*  h_bf  = (u16*)carve((size_t)M1 * PD * 2);
    u16*  h2_bf = (u16*)carve((size_t)M1 * DH * 2);
    u16*  W1T   = (u16*)carve((size_t)PD * PD * 2);
    u16*  W2T   = (u16*)carve((size_t)PD * DH * 2);
    u16*  W1bT  = (u16*)carve((size_t)BATCH * PD * PD * 2);
    u16*  W2bT  = (u16*)carve((size_t)BATCH * DH * PD * 2);
    float* b1b  = (float*)carve((size_t)BATCH * PD * 4);
    float* b2b  = (float*)carve((size_t)BATCH * DH * 4);
    float* h2m  = (float*)carve((size_t)BATCH * DH * 4);
    float* h2m2 = (float*)carve((size_t)BATCH * DH * 4);
    float* base = (float*)carve((size_t)BATCH * FD * 4);
    float* hid  = (float*)carve((size_t)BATCH * MH * 4);
    float* cf   = (float*)carve((size_t)BATCH * NT * 4);

    // 1. patchify -> bf16
    {
        int total = M1 * PD;
        patchify_bf<<<(total + 255) / 256, 256, 0, stream>>>(x, p_bf, total);
    }
    // 2. transpose shared weights (both in one launch: 576 + 2304 tiles)
    wtrans2<<<2880, 256, 0, stream>>>(W1, W1T, W2, W2T);
    // 3. phase-1 L1: h = relu(p @ W1 + b1)   M=6272 -> 25 tiles of 256
    gemm_bf16<<<dim3(PD / GBN, 25, 1), 512, 0, stream>>>(
        p_bf, W1T, b1, h_bf, M1, PD, PD, 0, 0, 0, 0, 1);
    // 4. phase-1 L2: h2 = relu(h @ W2 + b2)
    gemm_bf16<<<dim3(DH / GBN, 25, 1), 512, 0, stream>>>(
        h_bf, W2T, b2, h2_bf, M1, DH, PD, 0, 0, 0, 0, 1);
    // 5. mean pool -> h2m
    meanpool_bf<<<(BATCH * DH / 8 + 255) / 256, 256, 0, stream>>>(h2_bf, h2m, BATCH * DH / 8, DH);
    // 6. base = h2m @ W3 + b3
    compose_bias<<<(BATCH * FD + 255) / 256, 256, 0, stream>>>(b3, nullptr, nullptr, base, FD);
    skinny3<<<dim3(FD / 64, 1, 24), 256, 0, stream>>>(h2m, W3, nullptr, nullptr, base, DH / 24);
    // 7. hid = relu(base @ mW1 + mb1)
    hid_kernel<<<BATCH * MH / 4, 256, 0, stream>>>(base, mW1, mb1, hid);
    // 8. coefs
    coef_kernel<<<1, 256, 0, stream>>>(hid, mW2, mb2, cf);
    // 9. compose per-sample weights + biases
    compose_w<<<dim3(PD / 32, PD / 32), 256, 0, stream>>>(W1, dW1, cf, W1bT, PD, PD);
    compose_w<<<dim3(PD / 32, DH / 32), 256, 0, stream>>>(W2, dW2, cf, W2bT, PD, DH);
    compose_bias2<<<(BATCH * (PD + DH) + 255) / 256, 256, 0, stream>>>(b1, db1, b2, db2, cf, b1b, b2b);
    // 10. phase-2 L1: h = relu(p[b] @ W1b[b] + b1b[b])  single M-tile (196<=256)
    gemm_bf16<<<dim3(PD / GBN, 1, BATCH), 512, 0, stream>>>(
        p_bf, W1bT, b1b, h_bf, NPATCH, PD, PD,
        (long)NPATCH * PD, (long)PD * PD, (long)NPATCH * PD, PD, 1);
    // 11. phase-2 L2: h2 = relu(h[b] @ W2b[b] + b2b[b])  single M-tile, B read once
    gemm_bf16<<<dim3(DH / GBN, 1, BATCH), 512, 0, stream>>>(
        h_bf, W2bT, b2b, h2_bf, NPATCH, DH, PD,
        (long)NPATCH * PD, (long)DH * PD, (long)NPATCH * DH, DH, 1);
    // 12. mean pool -> h2m2
    meanpool_bf<<<(BATCH * DH / 8 + 255) / 256, 256, 0, stream>>>(h2_bf, h2m2, BATCH * DH / 8, DH);
    // 13. out = (b3 + sum c db3) + h2m2 @ W3 + sum_t c_t (h2m2 @ dW3[t])
    compose_bias<<<(BATCH * FD + 255) / 256, 256, 0, stream>>>(b3, db3, cf, out, FD);
    skinny3<<<dim3(FD / 64, 9, 6), 256, 0, stream>>>(h2m2, W3, dW3, cf, out, DH / 6);
}

// Round 5
// 546.008 us; speedup vs baseline: 1.2383x; 1.2383x over previous
//
#include <hip/hip_runtime.h>
#include <hip/hip_bf16.h>

// ---------------- problem constants ----------------
#define BATCH 32
#define NPATCH 196
#define PD 768
#define DH 3072
#define FD 512
#define MH 128
#define NT 8

typedef unsigned short u16;
typedef u16   u16x8  __attribute__((ext_vector_type(8)));
typedef short bf16x8 __attribute__((ext_vector_type(8)));
typedef float f32x4  __attribute__((ext_vector_type(4)));

__device__ __forceinline__ void async16(const void* g, void* l)
{
    __builtin_amdgcn_global_load_lds(
        (const __attribute__((address_space(1))) void*)g,
        (__attribute__((address_space(3))) void*)l, 16, 0, 0);
}

#define BARRIER() do { asm volatile("" ::: "memory"); __builtin_amdgcn_s_barrier(); asm volatile("" ::: "memory"); } while (0)
#define VMWAIT(n) asm volatile("s_waitcnt vmcnt(" #n ")" ::: "memory")

// =====================================================================
// Pipelined bf16 MFMA GEMM, K fixed = 768. C[z] = relu?(A[z]@BT[z]^T + bias[z])
// If pool!=0: skip C store; write pooled[z*N + n] = mean over M=196 rows.
// Tile 256x128, BK=32, 512 thr = 8 waves. 3-deep LDS ring, prefetch dist 2,
// raw s_barrier + explicit vmcnt (never a full drain inside the loop).
// =====================================================================
#define GK  768
#define NK  24          // GK/32
#define GBM 256
#define GBN 128
#define GBK 32
#define ASZ (GBM*GBK)   // 8192 u16 per buf
#define BSZ (GBN*GBK)   // 4096 u16 per buf

__global__ __launch_bounds__(512, 4)
void gemm_bf16(const u16* __restrict__ A, const u16* __restrict__ BT,
               const float* __restrict__ bias, u16* __restrict__ C,
               float* __restrict__ pooled,
               int M, int N, long sA, long sB, long sC, long sBias,
               int relu, int pool)
{
    const int z = blockIdx.z;
    A  += (long)z * sA;
    BT += (long)z * sB;
    C  += (long)z * sC;
    const float* bz = bias ? bias + (long)z * sBias : nullptr;

    __shared__ __align__(16) u16 As[3 * ASZ];   // 48 KB
    __shared__ __align__(16) u16 Bs[3 * BSZ];   // 24 KB

    const int tid  = threadIdx.x;
    const int lane = tid & 63;
    const int wave = tid >> 6;
    const int wr = (wave >> 1) * 64;
    const int wc = (wave & 1) * 64;
    const int m0 = blockIdx.y * GBM;
    const int n0 = blockIdx.x * GBN;
    const int lrow = lane & 15;
    const int koff = (lane >> 4) * 8;

    f32x4 acc[4][4] = {};

    auto issue = [&](int kt, int bi) {
        u16* asb = As + bi * ASZ;
        u16* bsb = Bs + bi * BSZ;
        const int k0 = kt * GBK;
#pragma unroll
        for (int r = 0; r < 2; ++r) {
            int chunk = r * 512 + tid;
            int row = chunk >> 2;
            int k8  = chunk & 3;
            int gm  = m0 + row; if (gm >= M) gm = M - 1;
            async16(A + (long)gm * GK + k0 + k8 * 8,
                    asb + (size_t)(r * 512 + wave * 64) * 8);
        }
        int rowb = tid >> 2;
        int k8b  = tid & 3;
        async16(BT + (long)(n0 + rowb) * GK + k0 + k8b * 8,
                bsb + (size_t)(wave * 64) * 8);
    };

    auto compute = [&](int bi) {
        const u16* asb = As + bi * ASZ;
        const u16* bsb = Bs + bi * BSZ;
        bf16x8 af[4], bfr[4];
#pragma unroll
        for (int i = 0; i < 4; ++i)
            af[i] = *(const bf16x8*)(asb + (wr + i * 16 + lrow) * GBK + koff);
#pragma unroll
        for (int j = 0; j < 4; ++j)
            bfr[j] = *(const bf16x8*)(bsb + (wc + j * 16 + lrow) * GBK + koff);
#pragma unroll
        for (int i = 0; i < 4; ++i)
#pragma unroll
            for (int j = 0; j < 4; ++j)
                acc[i][j] = __builtin_amdgcn_mfma_f32_16x16x32_bf16(af[i], bfr[j], acc[i][j], 0, 0, 0);
    };

    // prologue: tiles 0,1,2 in flight (9 loads/lane)
    issue(0, 0); issue(1, 1); issue(2, 2);

    // main: consume tile i, issue tile i+3 (21 iterations)
    for (int ii = 0; ii < 7; ++ii) {
        int i0 = ii * 3;
        VMWAIT(6); BARRIER(); compute(0); BARRIER(); issue(i0 + 3, 0);
        VMWAIT(6); BARRIER(); compute(1); BARRIER(); issue(i0 + 4, 1);
        VMWAIT(6); BARRIER(); compute(2); BARRIER(); issue(i0 + 5, 2);
    }
    // tail: tiles 21,22,23
    VMWAIT(6); BARRIER(); compute(0); BARRIER();
    VMWAIT(3); BARRIER(); compute(1); BARRIER();
    VMWAIT(0); BARRIER(); compute(2);

    const int crow = (lane >> 4) * 4;
    const int ccol = lane & 15;

    if (!pool) {
#pragma unroll
        for (int j = 0; j < 4; ++j) {
            int gn = n0 + wc + j * 16 + ccol;
            float bv = bz ? bz[gn] : 0.f;
#pragma unroll
            for (int i = 0; i < 4; ++i) {
#pragma unroll
                for (int rg = 0; rg < 4; ++rg) {
                    int gm = m0 + wr + i * 16 + crow + rg;
                    if (gm < M) {
                        float v = acc[i][j][rg] + bv;
                        if (relu) v = fmaxf(v, 0.f);
                        __hip_bfloat16 hv = __float2bfloat16(v);
                        C[(long)gm * N + gn] = *(u16*)&hv;
                    }
                }
            }
        }
    } else {
        // fused patch-mean: relu(acc+bias), sum rows<196, tree-reduce in LDS.
        float* poolbuf = (float*)As;   // 16*128 floats, alias (As no longer read)
        __syncthreads();               // all computes done before aliasing writes
        const int slot = (wave >> 1) * 4 + (lane >> 4);
#pragma unroll
        for (int j = 0; j < 4; ++j) {
            int gn = n0 + wc + j * 16 + ccol;
            float bv = bz ? bz[gn] : 0.f;
            float s = 0.f;
#pragma unroll
            for (int i = 0; i < 4; ++i) {
#pragma unroll
                for (int rg = 0; rg < 4; ++rg) {
                    int gm = wr + i * 16 + crow + rg;
                    if (gm < NPATCH) s += fmaxf(acc[i][j][rg] + bv, 0.f);
                }
            }
            poolbuf[slot * 128 + wc + j * 16 + ccol] = s;
        }
        __syncthreads();
        if (tid < 128) {
            float s = 0.f;
#pragma unroll
            for (int q = 0; q < 16; ++q) s += poolbuf[q * 128 + tid];
            pooled[(long)z * N + n0 + tid] = s * (1.0f / NPATCH);
        }
    }
}

// =====================================================================
// skinny layer-3 split-K (atomic): outp[b,f] += sum_k Aeff[b,k]*Bz[k,f]
// =====================================================================
#define L3CHUNK 128

__global__ __launch_bounds__(256)
void skinny3(const float* __restrict__ A, const float* __restrict__ B0,
             const float* __restrict__ dB, const float* __restrict__ cf,
             float* __restrict__ outp, int kchunk)
{
    const int z  = blockIdx.y;
    const int k0 = blockIdx.z * kchunk;
    const float* B = (z == 0) ? B0 : dB + (long)(z - 1) * DH * FD;

    __shared__ float Asl[BATCH][L3CHUNK];

    const int tid = threadIdx.x;
    const int n   = blockIdx.x * 64 + (tid & 63);
    const int bg  = tid >> 6;

    float acc[8] = {};

    for (int kc = 0; kc < kchunk; kc += L3CHUNK) {
#pragma unroll
        for (int r = 0; r < 16; ++r) {
            int idx = tid + r * 256;
            int b = idx >> 7;
            int k = idx & 127;
            float s = (z == 0) ? 1.f : cf[b * NT + z - 1];
            Asl[b][k] = s * A[(long)b * DH + k0 + kc + k];
        }
        __syncthreads();
#pragma unroll 4
        for (int k = 0; k < L3CHUNK; ++k) {
            float w = B[(long)(k0 + kc + k) * FD + n];
#pragma unroll
            for (int bb = 0; bb < 8; ++bb)
                acc[bb] = fmaf(Asl[bg * 8 + bb][k], w, acc[bb]);
        }
        __syncthreads();
    }
#pragma unroll
    for (int bb = 0; bb < 8; ++bb)
        atomicAdd(&outp[(long)(bg * 8 + bb) * FD + n], acc[bb]);
}

// ---------------- patchify -> bf16 ----------------
__global__ void patchify_bf(const float* __restrict__ x, u16* __restrict__ p, int total)
{
    int i = blockIdx.x * blockDim.x + threadIdx.x;
    if (i >= total) return;
    int d = i % PD;
    int rest = i / PD;
    int patch = rest % NPATCH;
    int b = rest / NPATCH;
    int c = d >> 8;
    int r = (d >> 4) & 15;
    int s = d & 15;
    int pr = patch / 14;
    int pc = patch % 14;
    float v = x[((long)(b * 3 + c) * 224 + (pr * 16 + r)) * 224 + (pc * 16 + s)];
    __hip_bfloat16 hv = __float2bfloat16(v);
    p[i] = *(u16*)&hv;
}

// ---------------- shared-weight transposes (one launch) ----------------
__global__ __launch_bounds__(256)
void wtrans2(const float* __restrict__ W1, u16* __restrict__ o1,
             const float* __restrict__ W2, u16* __restrict__ o2)
{
    const float* W; u16* outp; int K, N, t;
    if (blockIdx.x < 576) { W = W1; outp = o1; K = PD; N = PD;  t = blockIdx.x; }
    else                  { W = W2; outp = o2; K = PD; N = DH;  t = blockIdx.x - 576; }
    int nt = N / 32;
    int k0 = (t / nt) * 32;
    int n0 = (t % nt) * 32;

    __shared__ float Ws[32][33];
    const int tid = threadIdx.x;
#pragma unroll
    for (int r = 0; r < 4; ++r) {
        int idx = tid + r * 256;
        int kk = idx >> 5, nn = idx & 31;
        Ws[kk][nn] = W[(long)(k0 + kk) * N + n0 + nn];
    }
    __syncthreads();
#pragma unroll
    for (int r = 0; r < 4; ++r) {
        int idx = tid + r * 256;
        int kk = idx & 31, nn = idx >> 5;
        __hip_bfloat16 hv = __float2bfloat16(Ws[kk][nn]);
        outp[(long)(n0 + nn) * K + k0 + kk] = *(u16*)&hv;
    }
}

// ---------------- composed weights: out[b][n][k] = W[k][n] + sum_t cf dW ----
// 128 threads, tile 32k x 32n; register-resident W+8dW per thread.
__global__ __launch_bounds__(128)
void compose_w(const float* __restrict__ W, const float* __restrict__ dW,
               const float* __restrict__ cf, u16* __restrict__ out,
               int K, int N)
{
    __shared__ float Ws[9][32][32];
    const int tid = threadIdx.x;
    const int k0 = blockIdx.x * 32;
    const int n0 = blockIdx.y * 32;
    const long tKN = (long)K * N;

#pragma unroll
    for (int a = 0; a < 9; ++a) {
        const float* src = (a == 0) ? W : dW + (long)(a - 1) * tKN;
#pragma unroll
        for (int r = 0; r < 8; ++r) {
            int idx = tid + r * 128;
            int kk = idx >> 5, nn = idx & 31;
            Ws[a][kk][nn] = src[(long)(k0 + kk) * N + n0 + nn];
        }
    }
    __syncthreads();

    const int nn = tid >> 2;
    const int k8 = (tid & 3) * 8;
    float w0[8], d[NT][8];
#pragma unroll
    for (int q = 0; q < 8; ++q) w0[q] = Ws[0][k8 + q][nn];
#pragma unroll
    for (int t = 0; t < NT; ++t)
#pragma unroll
        for (int q = 0; q < 8; ++q) d[t][q] = Ws[t + 1][k8 + q][nn];

    for (int b = 0; b < BATCH; ++b) {
        float c8[NT];
#pragma unroll
        for (int t = 0; t < NT; ++t) c8[t] = cf[b * NT + t];
        u16x8 o;
#pragma unroll
        for (int q = 0; q < 8; ++q) {
            float v = w0[q];
#pragma unroll
            for (int t = 0; t < NT; ++t) v = fmaf(c8[t], d[t][q], v);
            __hip_bfloat16 hv = __float2bfloat16(v);
            o[q] = *(u16*)&hv;
        }
        *(u16x8*)(out + ((long)b * N + (n0 + nn)) * K + k0 + k8) = o;
    }
}

// ---------------- composed biases b1b,b2b + out-init in one launch --------
__global__ void compose_bias3(const float* __restrict__ b1, const float* __restrict__ db1,
                              const float* __restrict__ b2, const float* __restrict__ db2,
                              const float* __restrict__ b3, const float* __restrict__ db3,
                              const float* __restrict__ cf,
                              float* __restrict__ o1, float* __restrict__ o2,
                              float* __restrict__ o3)
{
    int i = blockIdx.x * blockDim.x + threadIdx.x;
    const int t1 = BATCH * PD, t2 = BATCH * (PD + DH);
    const float* bs; const float* db; float* o; int N, j;
    if (i < t1)      { bs = b1; db = db1; o = o1; N = PD; j = i; }
    else if (i < t2) { bs = b2; db = db2; o = o2; N = DH; j = i - t1; }
    else {
        j = i - t2;
        if (j >= BATCH * FD) return;
        bs = b3; db = db3; o = o3; N = FD;
    }
    int n = j % N, b = j / N;
    float v = bs[n];
#pragma unroll
    for (int t = 0; t < NT; ++t) v = fmaf(cf[b * NT + t], db[(long)t * N + n], v);
    o[j] = v;
}

// ---------------- bias init (base, pre-coef) ----------------
__global__ void bias_init(const float* __restrict__ bsrc, float* __restrict__ out, int N)
{
    int i = blockIdx.x * blockDim.x + threadIdx.x;
    if (i >= BATCH * N) return;
    out[i] = bsrc[i % N];
}

// ---------------- metanet L1 ----------------
__global__ __launch_bounds__(256)
void hid_kernel(const float* __restrict__ base, const float* __restrict__ mW1,
                const float* __restrict__ mb1, float* __restrict__ hid)
{
    int gw   = blockIdx.x * 4 + (threadIdx.x >> 6);
    int lane = threadIdx.x & 63;
    int b = gw >> 7;
    int n = gw & 127;
    float s = 0.f;
#pragma unroll
    for (int i = 0; i < FD / 64; ++i) {
        int k = i * 64 + lane;
        s = fmaf(base[b * FD + k], mW1[k * MH + n], s);
    }
#pragma unroll
    for (int off = 32; off; off >>= 1) s += __shfl_down(s, off, 64);
    if (lane == 0) hid[gw] = fmaxf(s + mb1[n], 0.f);
}

// ---------------- metanet L2 ----------------
__global__ void coef_kernel(const float* __restrict__ hidden, const float* __restrict__ mW2,
                            const float* __restrict__ mb2, float* __restrict__ coefs)
{
    int i = threadIdx.x;
    int t = i & 7;
    int b = i >> 3;
    float s = mb2[t];
    for (int k = 0; k < MH; ++k)
        s = fmaf(hidden[b * MH + k], mW2[k * NT + t], s);
    coefs[i] = s;
}

// ---------------- launcher ----------------
extern "C" void kernel_launch(void* const* d_in, const int* in_sizes, int n_in,
                              void* d_out, int out_size, void* d_ws, size_t ws_size,
                              hipStream_t stream)
{
    const float* x   = (const float*)d_in[0];
    const float* W1  = (const float*)d_in[1];
    const float* b1  = (const float*)d_in[2];
    const float* W2  = (const float*)d_in[3];
    const float* b2  = (const float*)d_in[4];
    const float* W3  = (const float*)d_in[5];
    const float* b3  = (const float*)d_in[6];
    const float* dW1 = (const float*)d_in[7];
    const float* db1 = (const float*)d_in[8];
    const float* dW2 = (const float*)d_in[9];
    const float* db2 = (const float*)d_in[10];
    const float* dW3 = (const float*)d_in[11];
    const float* db3 = (const float*)d_in[12];
    const float* mW1 = (const float*)d_in[13];
    const float* mb1 = (const float*)d_in[14];
    const float* mW2 = (const float*)d_in[15];
    const float* mb2 = (const float*)d_in[16];
    float* out = (float*)d_out;
    (void)n_in; (void)in_sizes; (void)out_size; (void)ws_size;

    char* w = (char*)d_ws;
    auto carve = [&](size_t bytes) { void* q = (void*)w; w += (bytes + 255) & ~(size_t)255; return q; };
    const int M1 = BATCH * NPATCH;   // 6272

    u16*  p_bf  = (u16*)carve((size_t)M1 * PD * 2);
    u16*  h_bf  = (u16*)carve((size_t)M1 * PD * 2);
    u16*  W1T   = (u16*)carve((size_t)PD * PD * 2);
    u16*  W2T   = (u16*)carve((size_t)PD * DH * 2);
    u16*  W1bT  = (u16*)carve((size_t)BATCH * PD * PD * 2);
    u16*  W2bT  = (u16*)carve((size_t)BATCH * DH * PD * 2);
    float* b1b  = (float*)carve((size_t)BATCH * PD * 4);
    float* b2b  = (float*)carve((size_t)BATCH * DH * 4);
    float* h2m  = (float*)carve((size_t)BATCH * DH * 4);
    float* h2m2 = (float*)carve((size_t)BATCH * DH * 4);
    float* base = (float*)carve((size_t)BATCH * FD * 4);
    float* hid  = (float*)carve((size_t)BATCH * MH * 4);
    float* cf   = (float*)carve((size_t)BATCH * NT * 4);

    // 1. patchify -> bf16
    {
        int total = M1 * PD;
        patchify_bf<<<(total + 255) / 256, 256, 0, stream>>>(x, p_bf, total);
    }
    // 2. shared-weight transposes
    wtrans2<<<2880, 256, 0, stream>>>(W1, W1T, W2, W2T);
    // 3. phase-1 L1: h = relu(p @ W1 + b1)
    gemm_bf16<<<dim3(PD / GBN, 25, 1), 512, 0, stream>>>(
        p_bf, W1T, b1, h_bf, nullptr, M1, PD, 0, 0, 0, 0, 1, 0);
    // 4. phase-1 L2 + fused patch-mean -> h2m (no h2 materialization)
    gemm_bf16<<<dim3(DH / GBN, 1, BATCH), 512, 0, stream>>>(
        h_bf, W2T, b2, nullptr, h2m, NPATCH, DH,
        (long)NPATCH * PD, 0, 0, 0, 1, 1);
    // 5. base = h2m @ W3 + b3
    bias_init<<<(BATCH * FD + 255) / 256, 256, 0, stream>>>(b3, base, FD);
    skinny3<<<dim3(FD / 64, 1, 24), 256, 0, stream>>>(h2m, W3, nullptr, nullptr, base, DH / 24);
    // 6. metanet
    hid_kernel<<<BATCH * MH / 4, 256, 0, stream>>>(base, mW1, mb1, hid);
    coef_kernel<<<1, 256, 0, stream>>>(hid, mW2, mb2, cf);
    // 7. compose per-sample weights + biases (+ out init)
    compose_w<<<dim3(PD / 32, PD / 32), 128, 0, stream>>>(W1, dW1, cf, W1bT, PD, PD);
    compose_w<<<dim3(PD / 32, DH / 32), 128, 0, stream>>>(W2, dW2, cf, W2bT, PD, DH);
    compose_bias3<<<(BATCH * (PD + DH + FD) + 255) / 256, 256, 0, stream>>>(
        b1, db1, b2, db2, b3, db3, cf, b1b, b2b, out);
    // 8. phase-2 L1: h = relu(p[b] @ W1b[b] + b1b[b])
    gemm_bf16<<<dim3(PD / GBN, 1, BATCH), 512, 0, stream>>>(
        p_bf, W1bT, b1b, h_bf, nullptr, NPATCH, PD,
        (long)NPATCH * PD, (long)PD * PD, (long)NPATCH * PD, PD, 1, 0);
    // 9. phase-2 L2 + fused patch-mean -> h2m2 (no h2, no W2bT re-read for pool)
    gemm_bf16<<<dim3(DH / GBN, 1, BATCH), 512, 0, stream>>>(
        h_bf, W2bT, b2b, nullptr, h2m2, NPATCH, DH,
        (long)NPATCH * PD, (long)DH * PD, 0, DH, 1, 1);
    // 10. out = (b3 + sum c db3) + h2m2 @ W3 + sum_t c_t (h2m2 @ dW3[t])
    skinny3<<<dim3(FD / 64, 9, 6), 256, 0, stream>>>(h2m2, W3, dW3, cf, out, DH / 6);
}

// Round 6
// 521.602 us; speedup vs baseline: 1.2962x; 1.0468x over previous
//
#include <hip/hip_runtime.h>
#include <hip/hip_bf16.h>

// ---------------- problem constants ----------------
#define BATCH 32
#define NPATCH 196
#define PD 768
#define DH 3072
#define FD 512
#define MH 128
#define NT 8

typedef unsigned short u16;
typedef u16   u16x8  __attribute__((ext_vector_type(8)));
typedef short bf16x8 __attribute__((ext_vector_type(8)));
typedef float f32x4  __attribute__((ext_vector_type(4)));

__device__ __forceinline__ void async16(const void* g, void* l)
{
    __builtin_amdgcn_global_load_lds(
        (const __attribute__((address_space(1))) void*)g,
        (__attribute__((address_space(3))) void*)l, 16, 0, 0);
}

#define BARRIER() do { asm volatile("" ::: "memory"); __builtin_amdgcn_s_barrier(); asm volatile("" ::: "memory"); } while (0)
#define VMWAIT(n) asm volatile("s_waitcnt vmcnt(" #n ")" ::: "memory")

// =====================================================================
// Pipelined bf16 MFMA GEMM, K fixed = 768. C[z] = relu?(A[z]@BT[z]^T + bias[z])
// If pool!=0: skip C store; write pooled[z*N + n] = mean over M=196 rows.
// Tile 256x128, BK=32, 512 thr = 8 waves. 3-deep LDS ring, prefetch dist 2,
// raw s_barrier + explicit vmcnt (never a full drain inside the loop).
// =====================================================================
#define GK  768
#define NK  24
#define GBM 256
#define GBN 128
#define GBK 32
#define ASZ (GBM*GBK)
#define BSZ (GBN*GBK)

__global__ __launch_bounds__(512, 4)
void gemm_bf16(const u16* __restrict__ A, const u16* __restrict__ BT,
               const float* __restrict__ bias, u16* __restrict__ C,
               float* __restrict__ pooled,
               int M, int N, long sA, long sB, long sC, long sBias,
               int relu, int pool)
{
    const int z = blockIdx.z;
    A  += (long)z * sA;
    BT += (long)z * sB;
    C  += (long)z * sC;
    const float* bz = bias ? bias + (long)z * sBias : nullptr;

    __shared__ __align__(16) u16 As[3 * ASZ];
    __shared__ __align__(16) u16 Bs[3 * BSZ];

    const int tid  = threadIdx.x;
    const int lane = tid & 63;
    const int wave = tid >> 6;
    const int wr = (wave >> 1) * 64;
    const int wc = (wave & 1) * 64;
    const int m0 = blockIdx.y * GBM;
    const int n0 = blockIdx.x * GBN;
    const int lrow = lane & 15;
    const int koff = (lane >> 4) * 8;

    f32x4 acc[4][4] = {};

    auto issue = [&](int kt, int bi) {
        u16* asb = As + bi * ASZ;
        u16* bsb = Bs + bi * BSZ;
        const int k0 = kt * GBK;
#pragma unroll
        for (int r = 0; r < 2; ++r) {
            int chunk = r * 512 + tid;
            int row = chunk >> 2;
            int k8  = chunk & 3;
            int gm  = m0 + row; if (gm >= M) gm = M - 1;
            async16(A + (long)gm * GK + k0 + k8 * 8,
                    asb + (size_t)(r * 512 + wave * 64) * 8);
        }
        int rowb = tid >> 2;
        int k8b  = tid & 3;
        async16(BT + (long)(n0 + rowb) * GK + k0 + k8b * 8,
                bsb + (size_t)(wave * 64) * 8);
    };

    auto compute = [&](int bi) {
        const u16* asb = As + bi * ASZ;
        const u16* bsb = Bs + bi * BSZ;
        bf16x8 af[4], bfr[4];
#pragma unroll
        for (int i = 0; i < 4; ++i)
            af[i] = *(const bf16x8*)(asb + (wr + i * 16 + lrow) * GBK + koff);
#pragma unroll
        for (int j = 0; j < 4; ++j)
            bfr[j] = *(const bf16x8*)(bsb + (wc + j * 16 + lrow) * GBK + koff);
#pragma unroll
        for (int i = 0; i < 4; ++i)
#pragma unroll
            for (int j = 0; j < 4; ++j)
                acc[i][j] = __builtin_amdgcn_mfma_f32_16x16x32_bf16(af[i], bfr[j], acc[i][j], 0, 0, 0);
    };

    issue(0, 0); issue(1, 1); issue(2, 2);

    for (int ii = 0; ii < 7; ++ii) {
        int i0 = ii * 3;
        VMWAIT(6); BARRIER(); compute(0); BARRIER(); issue(i0 + 3, 0);
        VMWAIT(6); BARRIER(); compute(1); BARRIER(); issue(i0 + 4, 1);
        VMWAIT(6); BARRIER(); compute(2); BARRIER(); issue(i0 + 5, 2);
    }
    VMWAIT(6); BARRIER(); compute(0); BARRIER();
    VMWAIT(3); BARRIER(); compute(1); BARRIER();
    VMWAIT(0); BARRIER(); compute(2);

    const int crow = (lane >> 4) * 4;
    const int ccol = lane & 15;

    if (!pool) {
#pragma unroll
        for (int j = 0; j < 4; ++j) {
            int gn = n0 + wc + j * 16 + ccol;
            float bv = bz ? bz[gn] : 0.f;
#pragma unroll
            for (int i = 0; i < 4; ++i) {
#pragma unroll
                for (int rg = 0; rg < 4; ++rg) {
                    int gm = m0 + wr + i * 16 + crow + rg;
                    if (gm < M) {
                        float v = acc[i][j][rg] + bv;
                        if (relu) v = fmaxf(v, 0.f);
                        __hip_bfloat16 hv = __float2bfloat16(v);
                        C[(long)gm * N + gn] = *(u16*)&hv;
                    }
                }
            }
        }
    } else {
        float* poolbuf = (float*)As;
        __syncthreads();
        const int slot = (wave >> 1) * 4 + (lane >> 4);
#pragma unroll
        for (int j = 0; j < 4; ++j) {
            int gn = n0 + wc + j * 16 + ccol;
            float bv = bz ? bz[gn] : 0.f;
            float s = 0.f;
#pragma unroll
            for (int i = 0; i < 4; ++i) {
#pragma unroll
                for (int rg = 0; rg < 4; ++rg) {
                    int gm = wr + i * 16 + crow + rg;
                    if (gm < NPATCH) s += fmaxf(acc[i][j][rg] + bv, 0.f);
                }
            }
            poolbuf[slot * 128 + wc + j * 16 + ccol] = s;
        }
        __syncthreads();
        if (tid < 128) {
            float s = 0.f;
#pragma unroll
            for (int q = 0; q < 16; ++q) s += poolbuf[q * 128 + tid];
            pooled[(long)z * N + n0 + tid] = s * (1.0f / NPATCH);
        }
    }
}

// =====================================================================
// skinny layer-3 v2: partial[z*KS+ks][b][n] = sum_{k in chunk} Aeff[b,k]*Bz[k,f]
// z==0: Bz=W3, Aeff=A; z>=1: Bz=dB[z-1], Aeff=cf[b,z-1]*A.
// 256 thr = 64 n-thr (8 n each, two f32x4 B loads) x 4 b-groups (8 b each).
// A staged k-major in LDS (padded 36) -> 2 broadcast ds_read_b128 per k.
// =====================================================================
#define SK_KC  64          // k per block (DH/SK_KC = 48 splits)
#define SK_PAD 36          // 144B rows: 16B aligned, conflict-free b128

__global__ __launch_bounds__(256)
void skinny3(const float* __restrict__ A, const float* __restrict__ B0,
             const float* __restrict__ dB, const float* __restrict__ cf,
             float* __restrict__ partial)
{
    const int ks = blockIdx.x;
    const int z  = blockIdx.y;
    const int KS = gridDim.x;
    const int k0 = ks * SK_KC;
    const float* B = (z == 0) ? B0 : dB + (long)(z - 1) * DH * FD;

    __shared__ __align__(16) float Asl[SK_KC][SK_PAD];

    const int tid  = threadIdx.x;
    const int nthr = tid & 63;
    const int bg   = tid >> 6;
    const int n    = nthr * 8;

    // stage scaled A chunk, k-major (coalesced global reads)
    for (int idx = tid; idx < 32 * SK_KC; idx += 256) {
        int b = idx >> 6;
        int k = idx & (SK_KC - 1);
        float sc = (z == 0) ? 1.f : cf[b * NT + (z - 1)];
        Asl[k][b] = sc * A[(long)b * DH + k0 + k];
    }
    __syncthreads();

    f32x4 acc[8][2] = {};
    for (int k = 0; k < SK_KC; ++k) {
        const float* bp = B + (long)(k0 + k) * FD + n;
        f32x4 w0 = *(const f32x4*)bp;
        f32x4 w1 = *(const f32x4*)(bp + 4);
        f32x4 a0 = *(const f32x4*)&Asl[k][bg * 8];
        f32x4 a1 = *(const f32x4*)&Asl[k][bg * 8 + 4];
#pragma unroll
        for (int q = 0; q < 4; ++q) {
#pragma unroll
            for (int c = 0; c < 4; ++c) {
                acc[q][0][c]     = fmaf(a0[q], w0[c], acc[q][0][c]);
                acc[q][1][c]     = fmaf(a0[q], w1[c], acc[q][1][c]);
                acc[4 + q][0][c] = fmaf(a1[q], w0[c], acc[4 + q][0][c]);
                acc[4 + q][1][c] = fmaf(a1[q], w1[c], acc[4 + q][1][c]);
            }
        }
    }
    float* P = partial + ((long)(z * KS + ks) * BATCH + bg * 8) * FD + n;
#pragma unroll
    for (int bb = 0; bb < 8; ++bb) {
        *(f32x4*)(P + (long)bb * FD)     = acc[bb][0];
        *(f32x4*)(P + (long)bb * FD + 4) = acc[bb][1];
    }
}

// reduce: dst[i] += sum_{p in group} partial[p][i]; grid (64, G), per = count/G
__global__ __launch_bounds__(256)
void reduce_partials(const float* __restrict__ partial, float* __restrict__ dst, int per)
{
    int i  = blockIdx.x * 256 + threadIdx.x;     // 0..16383
    int p0 = blockIdx.y * per;
    float s = 0.f;
    for (int p = 0; p < per; ++p)
        s += partial[(long)(p0 + p) * (BATCH * FD) + i];
    atomicAdd(&dst[i], s);
}

// ---------------- patchify -> bf16 ----------------
__global__ void patchify_bf(const float* __restrict__ x, u16* __restrict__ p, int total)
{
    int i = blockIdx.x * blockDim.x + threadIdx.x;
    if (i >= total) return;
    int d = i % PD;
    int rest = i / PD;
    int patch = rest % NPATCH;
    int b = rest / NPATCH;
    int c = d >> 8;
    int r = (d >> 4) & 15;
    int s = d & 15;
    int pr = patch / 14;
    int pc = patch % 14;
    float v = x[((long)(b * 3 + c) * 224 + (pr * 16 + r)) * 224 + (pc * 16 + s)];
    __hip_bfloat16 hv = __float2bfloat16(v);
    p[i] = *(u16*)&hv;
}

// ---------------- shared-weight transposes (one launch) ----------------
__global__ __launch_bounds__(256)
void wtrans2(const float* __restrict__ W1, u16* __restrict__ o1,
             const float* __restrict__ W2, u16* __restrict__ o2)
{
    const float* W; u16* outp; int K, N, t;
    if (blockIdx.x < 576) { W = W1; outp = o1; K = PD; N = PD;  t = blockIdx.x; }
    else                  { W = W2; outp = o2; K = PD; N = DH;  t = blockIdx.x - 576; }
    int nt = N / 32;
    int k0 = (t / nt) * 32;
    int n0 = (t % nt) * 32;

    __shared__ float Ws[32][33];
    const int tid = threadIdx.x;
#pragma unroll
    for (int r = 0; r < 4; ++r) {
        int idx = tid + r * 256;
        int kk = idx >> 5, nn = idx & 31;
        Ws[kk][nn] = W[(long)(k0 + kk) * N + n0 + nn];
    }
    __syncthreads();
#pragma unroll
    for (int r = 0; r < 4; ++r) {
        int idx = tid + r * 256;
        int kk = idx & 31, nn = idx >> 5;
        __hip_bfloat16 hv = __float2bfloat16(Ws[kk][nn]);
        outp[(long)(n0 + nn) * K + k0 + kk] = *(u16*)&hv;
    }
}

// ---------------- composed weights: out[b][n][k] = W[k][n] + sum_t cf dW ----
__global__ __launch_bounds__(128)
void compose_w(const float* __restrict__ W, const float* __restrict__ dW,
               const float* __restrict__ cf, u16* __restrict__ out,
               int K, int N)
{
    __shared__ float Ws[9][32][32];
    const int tid = threadIdx.x;
    const int k0 = blockIdx.x * 32;
    const int n0 = blockIdx.y * 32;
    const long tKN = (long)K * N;

#pragma unroll
    for (int a = 0; a < 9; ++a) {
        const float* src = (a == 0) ? W : dW + (long)(a - 1) * tKN;
#pragma unroll
        for (int r = 0; r < 8; ++r) {
            int idx = tid + r * 128;
            int kk = idx >> 5, nn = idx & 31;
            Ws[a][kk][nn] = src[(long)(k0 + kk) * N + n0 + nn];
        }
    }
    __syncthreads();

    const int nn = tid >> 2;
    const int k8 = (tid & 3) * 8;
    float w0[8], d[NT][8];
#pragma unroll
    for (int q = 0; q < 8; ++q) w0[q] = Ws[0][k8 + q][nn];
#pragma unroll
    for (int t = 0; t < NT; ++t)
#pragma unroll
        for (int q = 0; q < 8; ++q) d[t][q] = Ws[t + 1][k8 + q][nn];

    for (int b = 0; b < BATCH; ++b) {
        float c8[NT];
#pragma unroll
        for (int t = 0; t < NT; ++t) c8[t] = cf[b * NT + t];
        u16x8 o;
#pragma unroll
        for (int q = 0; q < 8; ++q) {
            float v = w0[q];
#pragma unroll
            for (int t = 0; t < NT; ++t) v = fmaf(c8[t], d[t][q], v);
            __hip_bfloat16 hv = __float2bfloat16(v);
            o[q] = *(u16*)&hv;
        }
        *(u16x8*)(out + ((long)b * N + (n0 + nn)) * K + k0 + k8) = o;
    }
}

// ---------------- composed biases b1b,b2b + out-init in one launch --------
__global__ void compose_bias3(const float* __restrict__ b1, const float* __restrict__ db1,
                              const float* __restrict__ b2, const float* __restrict__ db2,
                              const float* __restrict__ b3, const float* __restrict__ db3,
                              const float* __restrict__ cf,
                              float* __restrict__ o1, float* __restrict__ o2,
                              float* __restrict__ o3)
{
    int i = blockIdx.x * blockDim.x + threadIdx.x;
    const int t1 = BATCH * PD, t2 = BATCH * (PD + DH);
    const float* bs; const float* db; float* o; int N, j;
    if (i < t1)      { bs = b1; db = db1; o = o1; N = PD; j = i; }
    else if (i < t2) { bs = b2; db = db2; o = o2; N = DH; j = i - t1; }
    else {
        j = i - t2;
        if (j >= BATCH * FD) return;
        bs = b3; db = db3; o = o3; N = FD;
    }
    int n = j % N, b = j / N;
    float v = bs[n];
#pragma unroll
    for (int t = 0; t < NT; ++t) v = fmaf(cf[b * NT + t], db[(long)t * N + n], v);
    o[j] = v;
}

// ---------------- bias init (base, pre-coef) ----------------
__global__ void bias_init(const float* __restrict__ bsrc, float* __restrict__ out, int N)
{
    int i = blockIdx.x * blockDim.x + threadIdx.x;
    if (i >= BATCH * N) return;
    out[i] = bsrc[i % N];
}

// ---------------- metanet L1 ----------------
__global__ __launch_bounds__(256)
void hid_kernel(const float* __restrict__ base, const float* __restrict__ mW1,
                const float* __restrict__ mb1, float* __restrict__ hid)
{
    int gw   = blockIdx.x * 4 + (threadIdx.x >> 6);
    int lane = threadIdx.x & 63;
    int b = gw >> 7;
    int n = gw & 127;
    float s = 0.f;
#pragma unroll
    for (int i = 0; i < FD / 64; ++i) {
        int k = i * 64 + lane;
        s = fmaf(base[b * FD + k], mW1[k * MH + n], s);
    }
#pragma unroll
    for (int off = 32; off; off >>= 1) s += __shfl_down(s, off, 64);
    if (lane == 0) hid[gw] = fmaxf(s + mb1[n], 0.f);
}

// ---------------- metanet L2 ----------------
__global__ void coef_kernel(const float* __restrict__ hidden, const float* __restrict__ mW2,
                            const float* __restrict__ mb2, float* __restrict__ coefs)
{
    int i = threadIdx.x;
    int t = i & 7;
    int b = i >> 3;
    float s = mb2[t];
    for (int k = 0; k < MH; ++k)
        s = fmaf(hidden[b * MH + k], mW2[k * NT + t], s);
    coefs[i] = s;
}

// ---------------- launcher ----------------
extern "C" void kernel_launch(void* const* d_in, const int* in_sizes, int n_in,
                              void* d_out, int out_size, void* d_ws, size_t ws_size,
                              hipStream_t stream)
{
    const float* x   = (const float*)d_in[0];
    const float* W1  = (const float*)d_in[1];
    const float* b1  = (const float*)d_in[2];
    const float* W2  = (const float*)d_in[3];
    const float* b2  = (const float*)d_in[4];
    const float* W3  = (const float*)d_in[5];
    const float* b3  = (const float*)d_in[6];
    const float* dW1 = (const float*)d_in[7];
    const float* db1 = (const float*)d_in[8];
    const float* dW2 = (const float*)d_in[9];
    const float* db2 = (const float*)d_in[10];
    const float* dW3 = (const float*)d_in[11];
    const float* db3 = (const float*)d_in[12];
    const float* mW1 = (const float*)d_in[13];
    const float* mb1 = (const float*)d_in[14];
    const float* mW2 = (const float*)d_in[15];
    const float* mb2 = (const float*)d_in[16];
    float* out = (float*)d_out;
    (void)n_in; (void)in_sizes; (void)out_size; (void)ws_size;

    char* w = (char*)d_ws;
    auto carve = [&](size_t bytes) { void* q = (void*)w; w += (bytes + 255) & ~(size_t)255; return q; };
    const int M1 = BATCH * NPATCH;   // 6272
    const int KSPLITS = DH / SK_KC;  // 48

    u16*  p_bf  = (u16*)carve((size_t)M1 * PD * 2);
    u16*  h_bf  = (u16*)carve((size_t)M1 * PD * 2);
    u16*  W1T   = (u16*)carve((size_t)PD * PD * 2);
    u16*  W2T   = (u16*)carve((size_t)PD * DH * 2);
    u16*  W1bT  = (u16*)carve((size_t)BATCH * PD * PD * 2);
    u16*  W2bT  = (u16*)carve((size_t)BATCH * DH * PD * 2);
    float* b1b  = (float*)carve((size_t)BATCH * PD * 4);
    float* b2b  = (float*)carve((size_t)BATCH * DH * 4);
    float* h2m  = (float*)carve((size_t)BATCH * DH * 4);
    float* h2m2 = (float*)carve((size_t)BATCH * DH * 4);
    float* base = (float*)carve((size_t)BATCH * FD * 4);
    float* hid  = (float*)carve((size_t)BATCH * MH * 4);
    float* cf   = (float*)carve((size_t)BATCH * NT * 4);
    float* part = (float*)carve((size_t)9 * KSPLITS * BATCH * FD * 4);  // 28.3 MB

    // 1. patchify -> bf16
    {
        int total = M1 * PD;
        patchify_bf<<<(total + 255) / 256, 256, 0, stream>>>(x, p_bf, total);
    }
    // 2. shared-weight transposes
    wtrans2<<<2880, 256, 0, stream>>>(W1, W1T, W2, W2T);
    // 3. phase-1 L1: h = relu(p @ W1 + b1)
    gemm_bf16<<<dim3(PD / GBN, 25, 1), 512, 0, stream>>>(
        p_bf, W1T, b1, h_bf, nullptr, M1, PD, 0, 0, 0, 0, 1, 0);
    // 4. phase-1 L2 + fused patch-mean -> h2m
    gemm_bf16<<<dim3(DH / GBN, 1, BATCH), 512, 0, stream>>>(
        h_bf, W2T, b2, nullptr, h2m, NPATCH, DH,
        (long)NPATCH * PD, 0, 0, 0, 1, 1);
    // 5. base = h2m @ W3 + b3  (skinny split-K -> partials -> reduce)
    bias_init<<<(BATCH * FD + 255) / 256, 256, 0, stream>>>(b3, base, FD);
    skinny3<<<dim3(KSPLITS, 1), 256, 0, stream>>>(h2m, W3, nullptr, nullptr, part);
    reduce_partials<<<dim3(BATCH * FD / 256, 8), 256, 0, stream>>>(part, base, KSPLITS / 8);
    // 6. metanet
    hid_kernel<<<BATCH * MH / 4, 256, 0, stream>>>(base, mW1, mb1, hid);
    coef_kernel<<<1, 256, 0, stream>>>(hid, mW2, mb2, cf);
    // 7. compose per-sample weights + biases (+ out init)
    compose_w<<<dim3(PD / 32, PD / 32), 128, 0, stream>>>(W1, dW1, cf, W1bT, PD, PD);
    compose_w<<<dim3(PD / 32, DH / 32), 128, 0, stream>>>(W2, dW2, cf, W2bT, PD, DH);
    compose_bias3<<<(BATCH * (PD + DH + FD) + 255) / 256, 256, 0, stream>>>(
        b1, db1, b2, db2, b3, db3, cf, b1b, b2b, out);
    // 8. phase-2 L1: h = relu(p[b] @ W1b[b] + b1b[b])
    gemm_bf16<<<dim3(PD / GBN, 1, BATCH), 512, 0, stream>>>(
        p_bf, W1bT, b1b, h_bf, nullptr, NPATCH, PD,
        (long)NPATCH * PD, (long)PD * PD, (long)NPATCH * PD, PD, 1, 0);
    // 9. phase-2 L2 + fused patch-mean -> h2m2
    gemm_bf16<<<dim3(DH / GBN, 1, BATCH), 512, 0, stream>>>(
        h_bf, W2bT, b2b, nullptr, h2m2, NPATCH, DH,
        (long)NPATCH * PD, (long)DH * PD, 0, DH, 1, 1);
    // 10. out += h2m2 @ W3 + sum_t c_t (h2m2 @ dW3[t])   (out pre-init w/ bias)
    skinny3<<<dim3(KSPLITS, 9), 256, 0, stream>>>(h2m2, W3, dW3, cf, part);
    reduce_partials<<<dim3(BATCH * FD / 256, 8), 256, 0, stream>>>(part, out, 9 * KSPLITS / 8);
}